// Round 4
// baseline (172.150 us; speedup 1.0000x reference)
//
#include <hip/hip_runtime.h>
#include <hip/hip_bf16.h>
#include <math.h>

#define NN 13
#define SS 128
#define HH 768
#define DD 512

typedef __attribute__((ext_vector_type(8))) short bf16x8;
typedef __attribute__((ext_vector_type(4))) float f32x4;

__device__ __forceinline__ float gelu_f(float x) {
    return 0.5f * x * (1.0f + erff(x * 0.7071067811865475f));
}
__device__ __forceinline__ ushort f2b(float v) {
    __hip_bfloat16 h = __float2bfloat16(v);
    return *reinterpret_cast<ushort*>(&h);
}
__device__ __forceinline__ float b2f(ushort u) {
    __hip_bfloat16 h = *reinterpret_cast<__hip_bfloat16*>(&u);
    return __bfloat162float(h);
}

__device__ __forceinline__ int shape_hash(const int* __restrict__ active,
                                          const int* __restrict__ is_leaf, int b) {
    unsigned long long acc = 0ull, w = 1ull;
    for (int i = 0; i < NN; ++i) {
        unsigned long long p = (unsigned long long)(active[b*NN + i] * 2 + is_leaf[b*NN + i]);
        acc += p * w;
        w *= 31ull;
    }
    long long h = (long long)acc;
    if (h < 0) h = -h;
    return (int)(h % 256);
}

// ---------- weight transpose + bf16 cast: W[K][512] f32 -> WT[512][K] bf16 ----------
__global__ __launch_bounds__(256)
void transpose_weights(const float* __restrict__ Wl1, const float* __restrict__ Wl2,
                       const float* __restrict__ Wm1, const float* __restrict__ Wm2,
                       ushort* __restrict__ Tl1, ushort* __restrict__ Tl2,
                       ushort* __restrict__ Tm1, ushort* __restrict__ Tm2)
{
    int bx = blockIdx.x;
    const float* W; ushort* T; int K, tile;
    if (bx < 384)       { W = Wl1; T = Tl1; K = 768;  tile = bx; }
    else if (bx < 640)  { W = Wl2; T = Tl2; K = 512;  tile = bx - 384; }
    else if (bx < 1152) { W = Wm1; T = Tm1; K = 1024; tile = bx - 640; }
    else                { W = Wm2; T = Tm2; K = 512;  tile = bx - 1152; }
    int tk = tile >> 4, tj = tile & 15;
    __shared__ float lds[32][33];
    int t = threadIdx.x;
    int r = t >> 3, c0 = (t & 7) * 4;
    const float4 v = *(const float4*)(W + (size_t)(tk*32 + r)*DD + tj*32 + c0);
    lds[r][c0+0] = v.x; lds[r][c0+1] = v.y; lds[r][c0+2] = v.z; lds[r][c0+3] = v.w;
    __syncthreads();
    ushort* dst = T + (size_t)(tj*32 + r)*K + tk*32 + c0;
    dst[0] = f2b(lds[c0+0][r]); dst[1] = f2b(lds[c0+1][r]);
    dst[2] = f2b(lds[c0+2][r]); dst[3] = f2b(lds[c0+3][r]);
}

// ---------- pool partials: block = (unit R, s-quarter q); 192 thr, float4 lanes ----------
__global__ __launch_bounds__(192)
void pool_partial(const float* __restrict__ ls, const int* __restrict__ masks,
                  const int* __restrict__ is_leaf,
                  float* __restrict__ part, float* __restrict__ cntbuf)
{
    int idx = blockIdx.x;
    int R = idx >> 2, q = idx & 3;
    int n = R >> 6, b = R & 63;
    if (!is_leaf[b*NN + n]) return;
    const float4* src = (const float4*)(ls + (size_t)(b*NN + n) * SS * HH + (size_t)q * 32 * HH);
    const int* mk = masks + (b*NN + n) * SS + q * 32;
    int t = threadIdx.x;

    __shared__ float lsm[32];
    if (t < 32) lsm[t] = (float)mk[t];
    __syncthreads();

    float4 a = {0.f, 0.f, 0.f, 0.f};
    float cnt = 0.f;
    #pragma unroll 16
    for (int s = 0; s < 32; ++s) {
        float m = lsm[s];
        float4 v = src[s * (HH/4) + t];
        a.x += m * v.x; a.y += m * v.y; a.z += m * v.z; a.w += m * v.w;
        cnt += m;
    }
    ((float4*)(part + ((size_t)q * 832 + R) * HH))[t] = a;
    if (t == 0) cntbuf[q * 832 + R] = cnt;
}

// ---------- combine partials -> pooled (bf16); zeros for non-leaf units ----------
__global__ __launch_bounds__(192)
void pool_combine(const float* __restrict__ part, const float* __restrict__ cntbuf,
                  const int* __restrict__ is_leaf, ushort* __restrict__ pooled)
{
    int u = blockIdx.x;  // 0..831
    int n = u >> 6, b = u & 63;
    int t = threadIdx.x;
    ushort4* dst = (ushort4*)(pooled + (size_t)u * HH);
    if (!is_leaf[b*NN + n]) {
        ushort4 z = {0, 0, 0, 0};
        dst[t] = z;
        return;
    }
    float cnt = cntbuf[u] + cntbuf[832+u] + cntbuf[1664+u] + cntbuf[2496+u];
    float inv = 1.f / fmaxf(cnt, 1.f);
    float4 s = {0.f, 0.f, 0.f, 0.f};
    #pragma unroll
    for (int q = 0; q < 4; ++q) {
        float4 v = ((const float4*)(part + ((size_t)q * 832 + u) * HH))[t];
        s.x += v.x; s.y += v.y; s.z += v.z; s.w += v.w;
    }
    ushort4 o = { f2b(s.x*inv), f2b(s.y*inv), f2b(s.z*inv), f2b(s.w*inv) };
    dst[t] = o;
}

enum { LEAF_G1 = 0, LEAF_G2 = 1, MERGE_G1 = 2, MERGE_G2 = 3, FINAL_G2 = 4 };

// LDS-less MFMA GEMM: block = 64 rows x 64 cols, 4 waves, all operands direct
// from global (L2-resident). No __syncthreads in the K-loop -> fully pipelined.
template<int MODE, int KT>
__global__ __launch_bounds__(256)
void mfma_gemm(const ushort* __restrict__ Asrc, const ushort* __restrict__ WT,
               const float* __restrict__ bias, void* __restrict__ CoutV,
               const int* __restrict__ is_leaf, const int* __restrict__ active,
               const int* __restrict__ depth, const int* __restrict__ left,
               const int* __restrict__ right,
               const float* __restrict__ depth_emb, const float* __restrict__ shape_emb,
               const ushort* __restrict__ noderep,
               int n0, int n1, int n2)
{
    constexpr int NITER = KT / 32;

    const int t = threadIdx.x;
    const int lane = t & 63, wv = t >> 6;
    const int j0 = blockIdx.x * 64;
    const int by = blockIdx.y;
    const int lrow = lane & 15, lhi = lane >> 4;

    int node, lc = 0, rc = 0;
    if (MODE == LEAF_G1 || MODE == LEAF_G2) {
        node = by;
        bool anyleaf = __any(is_leaf[lane*NN + node] != 0);
        if (!anyleaf) {
            if (MODE == LEAF_G2) {           // zero-init this noderep column
                ushort* dst = (ushort*)CoutV + (size_t)(node*64)*DD;
                #pragma unroll
                for (int c = 0; c < 4; ++c) {
                    int jc = j0 + c*16 + lrow;
                    #pragma unroll
                    for (int reg = 0; reg < 4; ++reg) {
                        int rw = wv*16 + lhi*4 + reg;
                        dst[(size_t)rw*DD + jc] = 0;
                    }
                }
            }
            return;
        }
    } else {
        node = (by == 0) ? n0 : ((by == 1) ? n1 : n2);
        lc = left[node]; rc = right[node];
    }

    const int AK = (MODE == LEAF_G1) ? HH : DD;
    const int rowbase = (MODE == LEAF_G1 || MODE == LEAF_G2) ? node*64
                       : (MODE == MERGE_G1) ? 0 : by*64;
    const int arow = wv*16 + lrow;

    // per-lane base pointers (k-offset lhi*8 folded in)
    const ushort* apL;
    const ushort* apR = nullptr;
    if (MODE == MERGE_G1) {
        apL = noderep + (size_t)(lc*64 + arow)*DD + lhi*8;
        apR = noderep + (size_t)(rc*64 + arow)*DD + lhi*8;
    } else {
        apL = Asrc + (size_t)(rowbase + arow)*AK + lhi*8;
    }
    const ushort* bp0 = WT + (size_t)(j0 + 0*16 + lrow)*KT + lhi*8;
    const ushort* bp1 = WT + (size_t)(j0 + 1*16 + lrow)*KT + lhi*8;
    const ushort* bp2 = WT + (size_t)(j0 + 2*16 + lrow)*KT + lhi*8;
    const ushort* bp3 = WT + (size_t)(j0 + 3*16 + lrow)*KT + lhi*8;

    f32x4 acc[4];
    #pragma unroll
    for (int c = 0; c < 4; ++c) acc[c] = (f32x4){0.f, 0.f, 0.f, 0.f};

    #pragma unroll 4
    for (int kt = 0; kt < NITER; ++kt) {
        const int ko = kt*32;
        bf16x8 af;
        if (MODE == MERGE_G1) {
            af = (ko < DD) ? *(const bf16x8*)(apL + ko)
                           : *(const bf16x8*)(apR + (ko - DD));
        } else {
            af = *(const bf16x8*)(apL + ko);
        }
        bf16x8 b0 = *(const bf16x8*)(bp0 + ko);
        bf16x8 b1 = *(const bf16x8*)(bp1 + ko);
        bf16x8 b2 = *(const bf16x8*)(bp2 + ko);
        bf16x8 b3 = *(const bf16x8*)(bp3 + ko);
        acc[0] = __builtin_amdgcn_mfma_f32_16x16x32_bf16(af, b0, acc[0], 0, 0, 0);
        acc[1] = __builtin_amdgcn_mfma_f32_16x16x32_bf16(af, b1, acc[1], 0, 0, 0);
        acc[2] = __builtin_amdgcn_mfma_f32_16x16x32_bf16(af, b2, acc[2], 0, 0, 0);
        acc[3] = __builtin_amdgcn_mfma_f32_16x16x32_bf16(af, b3, acc[3], 0, 0, 0);
    }

    // ---------------- epilogue ----------------
    if (MODE == LEAF_G1) {
        ushort* H = (ushort*)CoutV + (size_t)(node*64)*DD;
        #pragma unroll
        for (int c = 0; c < 4; ++c) {
            int jc = j0 + c*16 + lrow;
            float bj = bias[jc];
            #pragma unroll
            for (int reg = 0; reg < 4; ++reg) {
                int rw = wv*16 + lhi*4 + reg;
                H[(size_t)rw*DD + jc] = f2b(gelu_f(acc[c][reg] + bj));
            }
        }
    } else if (MODE == LEAF_G2) {
        int dp = depth[node];
        const float* de = depth_emb + (size_t)dp*DD;
        bool lf[4];
        #pragma unroll
        for (int reg = 0; reg < 4; ++reg)
            lf[reg] = is_leaf[(wv*16 + lhi*4 + reg)*NN + node] != 0;
        ushort* dst = (ushort*)CoutV + (size_t)(node*64)*DD;
        #pragma unroll
        for (int c = 0; c < 4; ++c) {
            int jc = j0 + c*16 + lrow;
            float bj = bias[jc] + de[jc];
            #pragma unroll
            for (int reg = 0; reg < 4; ++reg) {
                int rw = wv*16 + lhi*4 + reg;
                dst[(size_t)rw*DD + jc] = f2b(lf[reg] ? (acc[c][reg] + bj) : 0.f);
            }
        }
    } else if (MODE == MERGE_G1) {
        ushort* Mh = (ushort*)CoutV + (size_t)(by*64)*DD;
        #pragma unroll
        for (int c = 0; c < 4; ++c) {
            int jc = j0 + c*16 + lrow;
            float bj = bias[jc];
            #pragma unroll
            for (int reg = 0; reg < 4; ++reg) {
                int rw = wv*16 + lhi*4 + reg;
                Mh[(size_t)rw*DD + jc] = f2b(gelu_f(acc[c][reg] + bj));
            }
        }
    } else {
        int dp = depth[node];
        const float* de = depth_emb + (size_t)dp*DD;
        bool anyInt = __any(active[lane*NN + node] && !is_leaf[lane*NN + node]);
        bool iv[4];
        #pragma unroll
        for (int reg = 0; reg < 4; ++reg) {
            int rw = wv*16 + lhi*4 + reg;
            iv[reg] = active[rw*NN + node] && !is_leaf[rw*NN + node];
        }
        if (MODE == MERGE_G2) {
            if (!anyInt) return;             // keep existing noderep column
            ushort* dst = (ushort*)CoutV + (size_t)(node*64)*DD;
            #pragma unroll
            for (int c = 0; c < 4; ++c) {
                int jc = j0 + c*16 + lrow;
                float bj = bias[jc] + de[jc];
                #pragma unroll
                for (int reg = 0; reg < 4; ++reg) {
                    int rw = wv*16 + lhi*4 + reg;
                    dst[(size_t)rw*DD + jc] = f2b(iv[reg] ? (acc[c][reg] + bj) : 0.f);
                }
            }
        } else {  // FINAL_G2 -> f32 out + shape_emb
            float* out = (float*)CoutV;
            int hh[4];
            #pragma unroll
            for (int reg = 0; reg < 4; ++reg)
                hh[reg] = shape_hash(active, is_leaf, wv*16 + lhi*4 + reg);
            #pragma unroll
            for (int c = 0; c < 4; ++c) {
                int jc = j0 + c*16 + lrow;
                float bj = bias[jc] + de[jc];
                #pragma unroll
                for (int reg = 0; reg < 4; ++reg) {
                    int rw = wv*16 + lhi*4 + reg;
                    float base = anyInt ? (iv[reg] ? (acc[c][reg] + bj) : 0.f)
                                        : b2f(noderep[(size_t)(node*64 + rw)*DD + jc]);
                    out[(size_t)rw*DD + jc] = base + shape_emb[(size_t)hh[reg]*DD + jc];
                }
            }
        }
    }
}

extern "C" void kernel_launch(void* const* d_in, const int* in_sizes, int n_in,
                              void* d_out, int out_size, void* d_ws, size_t ws_size,
                              hipStream_t stream)
{
    const int*   is_leaf     = (const int*)d_in[0];
    const int*   active      = (const int*)d_in[1];
    const int*   depth       = (const int*)d_in[2];
    const int*   left        = (const int*)d_in[3];
    const int*   right       = (const int*)d_in[4];
    const float* leaf_states = (const float*)d_in[5];
    const int*   leaf_masks  = (const int*)d_in[6];
    const float* Wl1 = (const float*)d_in[7];
    const float* bl1 = (const float*)d_in[8];
    const float* Wl2 = (const float*)d_in[9];
    const float* bl2 = (const float*)d_in[10];
    const float* Wm1 = (const float*)d_in[11];
    const float* bm1 = (const float*)d_in[12];
    const float* Wm2 = (const float*)d_in[13];
    const float* bm2 = (const float*)d_in[14];
    const float* depth_emb = (const float*)d_in[15];
    const float* shape_emb = (const float*)d_in[16];
    float* out = (float*)d_out;

    // ws layout: f32 region first, then bf16 (ushort) region; all 16B-aligned
    float* part   = (float*)d_ws;                 // 4*832*768 f32
    float* cntbuf = part + 4*832*768;             // 4*832 f32
    ushort* pooled  = (ushort*)(cntbuf + 4*832);  // 832*768 bf16
    ushort* hidden  = pooled + 832*768;           // 832*512
    ushort* noderep = hidden + 832*512;           // 832*512
    ushort* mhid    = noderep + 832*512;          // 3*64*512
    ushort* Tl1 = mhid + 3*64*512;                // 512*768
    ushort* Tl2 = Tl1 + 512*768;                  // 512*512
    ushort* Tm1 = Tl2 + 512*512;                  // 512*1024
    ushort* Tm2 = Tm1 + 512*1024;                 // 512*512

    transpose_weights<<<1408, 256, 0, stream>>>(Wl1, Wl2, Wm1, Wm2, Tl1, Tl2, Tm1, Tm2);

    pool_partial<<<832*4, 192, 0, stream>>>(leaf_states, leaf_masks, is_leaf, part, cntbuf);
    pool_combine<<<832, 192, 0, stream>>>(part, cntbuf, is_leaf, pooled);

    // leaf MLP (all nodes; no-leaf nodes short-circuit / zero-fill)
    mfma_gemm<LEAF_G1, 768><<<dim3(8, 13), 256, 0, stream>>>(
        pooled, Tl1, bl1, hidden, is_leaf, active, depth, left, right,
        depth_emb, shape_emb, noderep, 0, 0, 0);
    mfma_gemm<LEAF_G2, 512><<<dim3(8, 13), 256, 0, stream>>>(
        hidden, Tl2, bl2, noderep, is_leaf, active, depth, left, right,
        depth_emb, shape_emb, noderep, 0, 0, 0);

    // merge level 1: nodes {3,4,5}
    mfma_gemm<MERGE_G1, 1024><<<dim3(8, 3), 256, 0, stream>>>(
        nullptr, Tm1, bm1, mhid, is_leaf, active, depth, left, right,
        depth_emb, shape_emb, noderep, 3, 4, 5);
    mfma_gemm<MERGE_G2, 512><<<dim3(8, 3), 256, 0, stream>>>(
        mhid, Tm2, bm2, noderep, is_leaf, active, depth, left, right,
        depth_emb, shape_emb, noderep, 3, 4, 5);

    // merge level 2: nodes {1,2}
    mfma_gemm<MERGE_G1, 1024><<<dim3(8, 2), 256, 0, stream>>>(
        nullptr, Tm1, bm1, mhid, is_leaf, active, depth, left, right,
        depth_emb, shape_emb, noderep, 1, 2, 0);
    mfma_gemm<MERGE_G2, 512><<<dim3(8, 2), 256, 0, stream>>>(
        mhid, Tm2, bm2, noderep, is_leaf, active, depth, left, right,
        depth_emb, shape_emb, noderep, 1, 2, 0);

    // merge level 3: node {0} -> fused hash + shape_emb + f32 output
    mfma_gemm<MERGE_G1, 1024><<<dim3(8, 1), 256, 0, stream>>>(
        nullptr, Tm1, bm1, mhid, is_leaf, active, depth, left, right,
        depth_emb, shape_emb, noderep, 0, 0, 0);
    mfma_gemm<FINAL_G2, 512><<<dim3(8, 1), 256, 0, stream>>>(
        mhid, Tm2, bm2, out, is_leaf, active, depth, left, right,
        depth_emb, shape_emb, noderep, 0, 0, 0);
}